// Round 7
// baseline (321.585 us; speedup 1.0000x reference)
//
#include <hip/hip_runtime.h>
#include <cstdint>
#include <cstddef>

typedef unsigned long long ull;
typedef _Float16 f16x8 __attribute__((ext_vector_type(8)));
typedef float f32x4 __attribute__((ext_vector_type(4)));

#define N_ROWS 8192
#define SPAN   8187u   // n - k
#define MULT   1600u   // (2^32) % 8187
#define TAU_INV 10.0f
#define TOTAL_SAMP 163840u
#define INIT_KEY 0x7F800000FFFFFFFFull   // q=+inf, col=~0
#define NCHUNK 8
#define CHUNK_COLS 1024

// ---------------- threefry2x32 (JAX-compatible) ----------------
__device__ __forceinline__ void tf_round(unsigned &x0, unsigned &x1, int r) {
    x0 += x1; x1 = (x1 << r) | (x1 >> (32 - r)); x1 ^= x0;
}
__device__ __forceinline__ void threefry2x32(unsigned k0, unsigned k1,
                                             unsigned c0, unsigned c1,
                                             unsigned &o0, unsigned &o1) {
    unsigned ks2 = k0 ^ k1 ^ 0x1BD11BDAu;
    unsigned x0 = c0 + k0, x1 = c1 + k1;
    tf_round(x0, x1, 13); tf_round(x0, x1, 15); tf_round(x0, x1, 26); tf_round(x0, x1, 6);
    x0 += k1;  x1 += ks2 + 1u;
    tf_round(x0, x1, 17); tf_round(x0, x1, 29); tf_round(x0, x1, 16); tf_round(x0, x1, 24);
    x0 += ks2; x1 += k0 + 2u;
    tf_round(x0, x1, 13); tf_round(x0, x1, 15); tf_round(x0, x1, 26); tf_round(x0, x1, 6);
    x0 += k0;  x1 += k1 + 3u;
    tf_round(x0, x1, 17); tf_round(x0, x1, 29); tf_round(x0, x1, 16); tf_round(x0, x1, 24);
    x0 += k1;  x1 += ks2 + 4u;
    tf_round(x0, x1, 13); tf_round(x0, x1, 15); tf_round(x0, x1, 26); tf_round(x0, x1, 6);
    x0 += ks2; x1 += k0 + 5u;
    o0 = x0; o1 = x1;
}

__device__ __forceinline__ void insert5(ull* a, ull kk) {
    bool l3 = kk < a[3], l2 = kk < a[2], l1 = kk < a[1], l0 = kk < a[0];
    a[4] = l3 ? a[3] : kk;
    a[3] = l3 ? (l2 ? a[2] : kk) : a[3];
    a[2] = l2 ? (l1 ? a[1] : kk) : a[2];
    a[1] = l1 ? (l0 ? a[0] : kk) : a[1];
    a[0] = l0 ? kk : a[0];
}

__device__ __forceinline__ float wave_maxf(float v) {
#pragma unroll
    for (int o = 32; o; o >>= 1) v = fmaxf(v, __shfl_xor(v, o));
    return v;
}
__device__ __forceinline__ float wave_sumf(float v) {
#pragma unroll
    for (int o = 32; o; o >>= 1) v += __shfl_xor(v, o);
    return v;
}
__device__ __forceinline__ ull wave_minu64(ull v) {
#pragma unroll
    for (int o = 32; o; o >>= 1) {
        ull w = __shfl_xor(v, o);
        v = (w < v) ? w : v;
    }
    return v;
}

// ---------------- Kernel 1: norms + f16 hi/lo split ----------------
__global__ void prep_kernel(const float* __restrict__ X,
                            float2* __restrict__ nsiv,
                            char* __restrict__ Xhi,
                            char* __restrict__ Xlo) {
    int t = blockIdx.x * 256 + threadIdx.x;
    int row = t >> 3, c = t & 7;
    const float4* src = (const float4*)(X + (size_t)row * 64 + c * 8);
    float4 a = src[0], b = src[1];
    float v[8] = {a.x, a.y, a.z, a.w, b.x, b.y, b.z, b.w};
    float ss = 0.f;
#pragma unroll
    for (int j = 0; j < 8; ++j) ss = fmaf(v[j], v[j], ss);
    ss += __shfl_xor(ss, 1);
    ss += __shfl_xor(ss, 2);
    ss += __shfl_xor(ss, 4);
    f16x8 h, l;
#pragma unroll
    for (int j = 0; j < 8; ++j) {
        _Float16 hh = (_Float16)v[j];
        h[j] = hh;
        l[j] = (_Float16)(v[j] - (float)hh);
    }
    *(f16x8*)(Xhi + (size_t)row * 128 + c * 16) = h;
    *(f16x8*)(Xlo + (size_t)row * 128 + c * 16) = l;
    if (c == 0) nsiv[row] = make_float2(ss, 1.0f / (1.0f - fminf(ss, 1.0f)));
}

// ---------------- Kernel 2: MFMA gram + fused top-5 ----------------
// grid 1024 = 128 row-tiles x 8 col-chunks (1024 cols). 4 independent waves/block,
// 4 blocks/CU -> 4 waves/SIMD for latency hiding. ZERO LDS, ZERO barriers.
// B fragments straight from L2 (input is 2 MB, L2-resident).
__global__ __launch_bounds__(256, 4) void gram_topk(
        const char* __restrict__ Xhi, const char* __restrict__ Xlo,
        const float2* __restrict__ nsiv, ull* __restrict__ part) {
    const int t = threadIdx.x, lane = t & 63, wv = t >> 6;
    const int lx = lane & 15, lq = lane >> 4;
    const int r0 = (blockIdx.x >> 3) * 64;
    const int ch = blockIdx.x & 7;
    const int j0base = ch * CHUNK_COLS;

    // A fragments straight from global (one-time, 64B/lane)
    f16x8 ahi[2], alo[2];
#pragma unroll
    for (int kc = 0; kc < 2; ++kc) {
        const size_t aoff = (size_t)(r0 + wv * 16 + lx) * 128 + (kc * 4 + lq) * 16;
        ahi[kc] = *(const f16x8*)(Xhi + aoff);
        alo[kc] = *(const f16x8*)(Xlo + aoff);
    }

    // per-lane row stats (C/D layout: row = lq*4 + reg)
    int grow[4]; float rns[4];
#pragma unroll
    for (int r = 0; r < 4; ++r) {
        grow[r] = r0 + wv * 16 + lq * 4 + r;
        rns[r] = nsiv[grow[r]].x;
    }

    ull t5[4][5];
    float thr[4];
#pragma unroll
    for (int r = 0; r < 4; ++r) {
        thr[r] = __builtin_inff();
#pragma unroll
        for (int s = 0; s < 5; ++s) t5[r][s] = INIT_KEY;
    }

    for (int it = 0; it < CHUNK_COLS / 64; ++it) {
        const int j0 = j0base + it * 64;

        float2 cn[4];
#pragma unroll
        for (int ct = 0; ct < 4; ++ct) cn[ct] = nsiv[j0 + ct * 16 + lx];

        f32x4 acc[4];
#pragma unroll
        for (int ct = 0; ct < 4; ++ct) {
            const size_t boff = (size_t)(j0 + ct * 16 + lx) * 128;
            f16x8 bh0 = *(const f16x8*)(Xhi + boff + lq * 16);
            f16x8 bh1 = *(const f16x8*)(Xhi + boff + (4 + lq) * 16);
            f16x8 bl0 = *(const f16x8*)(Xlo + boff + lq * 16);
            f16x8 bl1 = *(const f16x8*)(Xlo + boff + (4 + lq) * 16);
            f32x4 a = {0.f, 0.f, 0.f, 0.f};
            a = __builtin_amdgcn_mfma_f32_16x16x32_f16(ahi[0], bh0, a, 0, 0, 0);
            a = __builtin_amdgcn_mfma_f32_16x16x32_f16(ahi[1], bh1, a, 0, 0, 0);
            a = __builtin_amdgcn_mfma_f32_16x16x32_f16(ahi[0], bl0, a, 0, 0, 0);
            a = __builtin_amdgcn_mfma_f32_16x16x32_f16(ahi[1], bl1, a, 0, 0, 0);
            a = __builtin_amdgcn_mfma_f32_16x16x32_f16(alo[0], bh0, a, 0, 0, 0);
            a = __builtin_amdgcn_mfma_f32_16x16x32_f16(alo[1], bh1, a, 0, 0, 0);
            acc[ct] = a;
        }

        // selection with monotone proxy q = d2 * civ_j
#pragma unroll
        for (int ct = 0; ct < 4; ++ct) {
            const float civ    = cn[ct].y;
            const float cnsciv = cn[ct].x * civ;
            const float m2civ  = -2.0f * civ;
            const int   gcol   = j0 + ct * 16 + lx;
#pragma unroll
            for (int r = 0; r < 4; ++r) {
                float base = fmaf(rns[r], civ, cnsciv);
                float q    = fmaf(acc[ct][r], m2civ, base);
                if (q < thr[r] && gcol != grow[r]) {
                    ull kk = ((ull)__float_as_uint(q) << 32) | (unsigned)gcol;
                    insert5(t5[r], kk);
                    thr[r] = __uint_as_float((unsigned)(t5[r][4] >> 32));
                }
            }
        }
    }

    // shuffle-based merge across the 16 lanes of each lq-group (rows lq*4+r).
    // t5[r] is sorted ascending -> local min is t5[r][0]; removal = shift left.
    ull outk[4][5];
#pragma unroll
    for (int r = 0; r < 4; ++r) {
#pragma unroll
        for (int s = 0; s < 5; ++s) {
            ull m = t5[r][0];
#pragma unroll
            for (int off = 1; off <= 8; off <<= 1) {
                ull w = __shfl_xor(m, off);
                m = (w < m) ? w : m;
            }
            if (t5[r][0] == m) {   // unique keys (col embedded) -> single owner
                t5[r][0] = t5[r][1]; t5[r][1] = t5[r][2];
                t5[r][2] = t5[r][3]; t5[r][3] = t5[r][4];
                t5[r][4] = ~0ull;
            }
            outk[r][s] = m;
        }
    }
#pragma unroll
    for (int r = 0; r < 4; ++r) {
        if (lx == r) {
            ull* dst = part + (size_t)(r0 + wv * 16 + lq * 4 + r) * (NCHUNK * 5) + ch * 5;
#pragma unroll
            for (int s = 0; s < 5; ++s) dst[s] = outk[r][s];
        }
    }
}

// ---------------- Kernel 3: finalize, 4 rows/block (wave per row), shuffle-parallel ----------------
__global__ __launch_bounds__(256) void finalize_kernel(
        const float* __restrict__ X, const float2* __restrict__ nsiv,
        const ull* __restrict__ part, float* __restrict__ rowloss) {
    const int t = threadIdx.x, lane = t & 63, wv = t >> 6;
    const int row = blockIdx.x * 4 + wv;

    // merge chunk top-5s (40 keys) -> global top-5 via 5 wave-min passes
    ull key = (lane < NCHUNK * 5) ? part[(size_t)row * (NCHUNK * 5) + lane] : ~0ull;
    ull b[5];
#pragma unroll
    for (int s = 0; s < 5; ++s) {
        ull m = wave_minu64(key);
        b[s] = m;
        if (key == m) key = ~0ull;   // cols unique across chunks -> unique min
    }

    int pcol[5], ids[5];
#pragma unroll
    for (int s = 0; s < 5; ++s) { pcol[s] = (int)(unsigned)(b[s] & 0xFFFFFFFFull); ids[s] = pcol[s]; }
    // sort excluded ids ascending (tiny; every lane duplicates)
    for (int i = 0; i < 4; ++i)
        for (int j = 0; j < 4 - i; ++j)
            if (ids[j] > ids[j + 1]) { int tmp = ids[j]; ids[j] = ids[j + 1]; ids[j + 1] = tmp; }

    // column for this lane: lanes 0..19 = sampled negatives, 20..24 = positives
    int col = row;
    if (lane < 20) {
        unsigned m0 = (unsigned)(row * 20 + lane);
        unsigned hi, lo;
        threefry2x32(0u, 42u, m0, m0 + TOTAL_SAMP, hi, lo);
        unsigned samp = ((hi % SPAN) * MULT + (lo % SPAN)) % SPAN;
        int c = (int)samp;
#pragma unroll
        for (int s = 0; s < 5; ++s) c += (ids[s] <= c) ? 1 : 0;
        col = c;
    } else if (lane < 25) {
        col = pcol[lane - 20];
    }

    // exact fp32 Poincare distance term  -dist/tau  (diagonal -> -inf)
    float term = -INFINITY;
    if (lane < 25 && col != row) {
        const float4* xr = (const float4*)(X + (size_t)row * 64);
        const float4* xc = (const float4*)(X + (size_t)col * 64);
        float dot = 0.f;
#pragma unroll
        for (int k = 0; k < 16; ++k) {
            float4 a = xr[k];
            float4 c = xc[k];
            dot = fmaf(a.x, c.x, dot);
            dot = fmaf(a.y, c.y, dot);
            dot = fmaf(a.z, c.z, dot);
            dot = fmaf(a.w, c.w, dot);
        }
        float nsi = nsiv[row].x, nsj = nsiv[col].x;
        float d2  = fmaxf(nsi + nsj - 2.f * dot, 0.f);
        float ci  = 1.f - fminf(nsi, 1.f);
        float cj  = 1.f - fminf(nsj, 1.f);
        float den = fmaxf(ci * cj, 1e-9f);
        float z   = fmaxf(1.f + 2.f * d2 / den, 1.f);
        term = -acoshf(z) * TAU_INV;
    }

    // two masked LSEs across the wave
    float negt = (lane < 20) ? term : -INFINITY;
    float post = (lane >= 20 && lane < 25) ? term : -INFINITY;

    float nm = wave_maxf(negt);
    float ne = (lane < 20 && negt != -INFINITY) ? expf(negt - nm) : 0.f;
    float neg = nm + logf(wave_sumf(ne));

    float pm = wave_maxf(post);
    float pe = (lane >= 20 && lane < 25) ? expf(post - pm) : 0.f;
    float pos = pm + logf(wave_sumf(pe));

    if (lane == 0) rowloss[row] = neg - pos;
}

// ---------------- Kernel 4: deterministic tree sum ----------------
__global__ void reduce_kernel(const float* __restrict__ rl, float* __restrict__ out) {
    const int t = threadIdx.x;
    float s = 0.f;
#pragma unroll
    for (int i = 0; i < 32; ++i) s += rl[t + 256 * i];
#pragma unroll
    for (int o = 32; o; o >>= 1) s += __shfl_xor(s, o);
    __shared__ float ws4[4];
    if ((t & 63) == 0) ws4[t >> 6] = s;
    __syncthreads();
    if (t == 0) out[0] = (ws4[0] + ws4[1] + ws4[2] + ws4[3]) * (1.0f / 8192.0f);
}

// ---------------- launch ----------------
extern "C" void kernel_launch(void* const* d_in, const int* in_sizes, int n_in,
                              void* d_out, int out_size, void* d_ws, size_t ws_size,
                              hipStream_t stream) {
    (void)in_sizes; (void)n_in; (void)out_size; (void)ws_size;
    const float* X = (const float*)d_in[0];
    float* out = (float*)d_out;

    float2* nsiv    = (float2*)d_ws;                                  // 64 KB
    char*   Xhi     = (char*)d_ws + 65536;                            // 1 MB
    char*   Xlo     = (char*)d_ws + 65536 + 1048576;                  // 1 MB
    ull*    part    = (ull*)((char*)d_ws + 65536 + 2097152);          // 8192*40*8 = 2.5 MB
    float*  rowloss = (float*)((char*)d_ws + 65536 + 2097152 + 2621440); // 32 KB

    prep_kernel<<<256, 256, 0, stream>>>(X, nsiv, Xhi, Xlo);
    gram_topk<<<1024, 256, 0, stream>>>(Xhi, Xlo, nsiv, part);
    finalize_kernel<<<2048, 256, 0, stream>>>(X, nsiv, part, rowloss);
    reduce_kernel<<<1, 256, 0, stream>>>(rowloss, out);
}

// Round 8
// 236.381 us; speedup vs baseline: 1.3605x; 1.3605x over previous
//
#include <hip/hip_runtime.h>
#include <cstdint>
#include <cstddef>

typedef unsigned long long ull;
typedef _Float16 f16x8 __attribute__((ext_vector_type(8)));
typedef float f32x4 __attribute__((ext_vector_type(4)));

#define N_ROWS 8192
#define SPAN   8187u   // n - k
#define MULT   1600u   // (2^32) % 8187
#define TAU_INV 10.0f
#define TOTAL_SAMP 163840u
#define INIT_KEY 0x7F800000FFFFFFFFull   // q=+inf, col=~0
#define NCHUNK 8
#define CHUNK_COLS 1024

// ---------------- threefry2x32 (JAX-compatible) ----------------
__device__ __forceinline__ void tf_round(unsigned &x0, unsigned &x1, int r) {
    x0 += x1; x1 = (x1 << r) | (x1 >> (32 - r)); x1 ^= x0;
}
__device__ __forceinline__ void threefry2x32(unsigned k0, unsigned k1,
                                             unsigned c0, unsigned c1,
                                             unsigned &o0, unsigned &o1) {
    unsigned ks2 = k0 ^ k1 ^ 0x1BD11BDAu;
    unsigned x0 = c0 + k0, x1 = c1 + k1;
    tf_round(x0, x1, 13); tf_round(x0, x1, 15); tf_round(x0, x1, 26); tf_round(x0, x1, 6);
    x0 += k1;  x1 += ks2 + 1u;
    tf_round(x0, x1, 17); tf_round(x0, x1, 29); tf_round(x0, x1, 16); tf_round(x0, x1, 24);
    x0 += ks2; x1 += k0 + 2u;
    tf_round(x0, x1, 13); tf_round(x0, x1, 15); tf_round(x0, x1, 26); tf_round(x0, x1, 6);
    x0 += k0;  x1 += k1 + 3u;
    tf_round(x0, x1, 17); tf_round(x0, x1, 29); tf_round(x0, x1, 16); tf_round(x0, x1, 24);
    x0 += k1;  x1 += ks2 + 4u;
    tf_round(x0, x1, 13); tf_round(x0, x1, 15); tf_round(x0, x1, 26); tf_round(x0, x1, 6);
    x0 += ks2; x1 += k0 + 5u;
    o0 = x0; o1 = x1;
}

__device__ __forceinline__ void insert5(ull* a, ull kk) {
    bool l3 = kk < a[3], l2 = kk < a[2], l1 = kk < a[1], l0 = kk < a[0];
    a[4] = l3 ? a[3] : kk;
    a[3] = l3 ? (l2 ? a[2] : kk) : a[3];
    a[2] = l2 ? (l1 ? a[1] : kk) : a[2];
    a[1] = l1 ? (l0 ? a[0] : kk) : a[1];
    a[0] = l0 ? kk : a[0];
}

__device__ __forceinline__ float wave_maxf(float v) {
#pragma unroll
    for (int o = 32; o; o >>= 1) v = fmaxf(v, __shfl_xor(v, o));
    return v;
}
__device__ __forceinline__ float wave_sumf(float v) {
#pragma unroll
    for (int o = 32; o; o >>= 1) v += __shfl_xor(v, o);
    return v;
}
__device__ __forceinline__ ull wave_minu64(ull v) {
#pragma unroll
    for (int o = 32; o; o >>= 1) {
        ull w = __shfl_xor(v, o);
        v = (w < v) ? w : v;
    }
    return v;
}

// ---------------- Kernel 1: norms + f16 hi/lo split ----------------
__global__ void prep_kernel(const float* __restrict__ X,
                            float2* __restrict__ nsiv,
                            char* __restrict__ Xhi,
                            char* __restrict__ Xlo) {
    int t = blockIdx.x * 256 + threadIdx.x;
    int row = t >> 3, c = t & 7;
    const float4* src = (const float4*)(X + (size_t)row * 64 + c * 8);
    float4 a = src[0], b = src[1];
    float v[8] = {a.x, a.y, a.z, a.w, b.x, b.y, b.z, b.w};
    float ss = 0.f;
#pragma unroll
    for (int j = 0; j < 8; ++j) ss = fmaf(v[j], v[j], ss);
    ss += __shfl_xor(ss, 1);
    ss += __shfl_xor(ss, 2);
    ss += __shfl_xor(ss, 4);
    f16x8 h, l;
#pragma unroll
    for (int j = 0; j < 8; ++j) {
        _Float16 hh = (_Float16)v[j];
        h[j] = hh;
        l[j] = (_Float16)(v[j] - (float)hh);
    }
    *(f16x8*)(Xhi + (size_t)row * 128 + c * 16) = h;
    *(f16x8*)(Xlo + (size_t)row * 128 + c * 16) = l;
    if (c == 0) nsiv[row] = make_float2(ss, 1.0f / (1.0f - fminf(ss, 1.0f)));
}

// ---------------- Kernel 2: MFMA gram + fused top-5 ----------------
// grid 1024 = 128 row-tiles x 8 col-chunks (1024 cols). 4 independent waves/block,
// 4 blocks/CU. ZERO LDS, ZERO barriers. NO VGPR clamp (round-7 lesson: a 64-VGPR
// cap spills t5/frags to scratch -> 183 MB of HBM traffic). ~100-110 VGPRs
// expected -> 4-5 waves/SIMD.
__global__ __launch_bounds__(256) void gram_topk(
        const char* __restrict__ Xhi, const char* __restrict__ Xlo,
        const float2* __restrict__ nsiv, ull* __restrict__ part) {
    const int t = threadIdx.x, lane = t & 63, wv = t >> 6;
    const int lx = lane & 15, lq = lane >> 4;
    const int r0 = (blockIdx.x >> 3) * 64;
    const int ch = blockIdx.x & 7;
    const int j0base = ch * CHUNK_COLS;

    // A fragments straight from global (one-time, 64B/lane)
    f16x8 ahi[2], alo[2];
#pragma unroll
    for (int kc = 0; kc < 2; ++kc) {
        const size_t aoff = (size_t)(r0 + wv * 16 + lx) * 128 + (kc * 4 + lq) * 16;
        ahi[kc] = *(const f16x8*)(Xhi + aoff);
        alo[kc] = *(const f16x8*)(Xlo + aoff);
    }

    // per-lane row stats (C/D layout: row = lq*4 + reg)
    int grow[4]; float rns[4];
#pragma unroll
    for (int r = 0; r < 4; ++r) {
        grow[r] = r0 + wv * 16 + lq * 4 + r;
        rns[r] = nsiv[grow[r]].x;
    }

    ull t5[4][5];
    float thr[4];
#pragma unroll
    for (int r = 0; r < 4; ++r) {
        thr[r] = __builtin_inff();
#pragma unroll
        for (int s = 0; s < 5; ++s) t5[r][s] = INIT_KEY;
    }

    for (int it = 0; it < CHUNK_COLS / 64; ++it) {
        const int j0 = j0base + it * 64;

        float2 cn[4];
#pragma unroll
        for (int ct = 0; ct < 4; ++ct) cn[ct] = nsiv[j0 + ct * 16 + lx];

        f32x4 acc[4];
#pragma unroll
        for (int ct = 0; ct < 4; ++ct) {
            const size_t boff = (size_t)(j0 + ct * 16 + lx) * 128;
            f16x8 bh0 = *(const f16x8*)(Xhi + boff + lq * 16);
            f16x8 bh1 = *(const f16x8*)(Xhi + boff + (4 + lq) * 16);
            f16x8 bl0 = *(const f16x8*)(Xlo + boff + lq * 16);
            f16x8 bl1 = *(const f16x8*)(Xlo + boff + (4 + lq) * 16);
            f32x4 a = {0.f, 0.f, 0.f, 0.f};
            a = __builtin_amdgcn_mfma_f32_16x16x32_f16(ahi[0], bh0, a, 0, 0, 0);
            a = __builtin_amdgcn_mfma_f32_16x16x32_f16(ahi[1], bh1, a, 0, 0, 0);
            a = __builtin_amdgcn_mfma_f32_16x16x32_f16(ahi[0], bl0, a, 0, 0, 0);
            a = __builtin_amdgcn_mfma_f32_16x16x32_f16(ahi[1], bl1, a, 0, 0, 0);
            a = __builtin_amdgcn_mfma_f32_16x16x32_f16(alo[0], bh0, a, 0, 0, 0);
            a = __builtin_amdgcn_mfma_f32_16x16x32_f16(alo[1], bh1, a, 0, 0, 0);
            acc[ct] = a;
        }

        // selection with monotone proxy q = d2 * civ_j
#pragma unroll
        for (int ct = 0; ct < 4; ++ct) {
            const float civ    = cn[ct].y;
            const float cnsciv = cn[ct].x * civ;
            const float m2civ  = -2.0f * civ;
            const int   gcol   = j0 + ct * 16 + lx;
#pragma unroll
            for (int r = 0; r < 4; ++r) {
                float base = fmaf(rns[r], civ, cnsciv);
                float q    = fmaf(acc[ct][r], m2civ, base);
                if (q < thr[r] && gcol != grow[r]) {
                    ull kk = ((ull)__float_as_uint(q) << 32) | (unsigned)gcol;
                    insert5(t5[r], kk);
                    thr[r] = __uint_as_float((unsigned)(t5[r][4] >> 32));
                }
            }
        }
    }

    // shuffle-based merge across the 16 lanes of each lq-group (rows lq*4+r).
    // t5[r] is sorted ascending -> local min is t5[r][0]; removal = shift left.
#pragma unroll
    for (int r = 0; r < 4; ++r) {
        ull outk[5];
#pragma unroll
        for (int s = 0; s < 5; ++s) {
            ull m = t5[r][0];
#pragma unroll
            for (int off = 1; off <= 8; off <<= 1) {
                ull w = __shfl_xor(m, off);
                m = (w < m) ? w : m;
            }
            if (t5[r][0] == m) {   // unique keys (col embedded) -> single owner
                t5[r][0] = t5[r][1]; t5[r][1] = t5[r][2];
                t5[r][2] = t5[r][3]; t5[r][3] = t5[r][4];
                t5[r][4] = ~0ull;
            }
            outk[s] = m;
        }
        if (lx == r) {
            ull* dst = part + (size_t)(r0 + wv * 16 + lq * 4 + r) * (NCHUNK * 5) + ch * 5;
#pragma unroll
            for (int s = 0; s < 5; ++s) dst[s] = outk[s];
        }
    }
}

// ---------------- Kernel 3: finalize, 4 rows/block (wave per row), shuffle-parallel ----------------
__global__ __launch_bounds__(256) void finalize_kernel(
        const float* __restrict__ X, const float2* __restrict__ nsiv,
        const ull* __restrict__ part, float* __restrict__ rowloss) {
    const int t = threadIdx.x, lane = t & 63, wv = t >> 6;
    const int row = blockIdx.x * 4 + wv;

    // merge chunk top-5s (40 keys) -> global top-5 via 5 wave-min passes
    ull key = (lane < NCHUNK * 5) ? part[(size_t)row * (NCHUNK * 5) + lane] : ~0ull;
    ull b[5];
#pragma unroll
    for (int s = 0; s < 5; ++s) {
        ull m = wave_minu64(key);
        b[s] = m;
        if (key == m) key = ~0ull;   // cols unique across chunks -> unique min
    }

    int pcol[5], ids[5];
#pragma unroll
    for (int s = 0; s < 5; ++s) { pcol[s] = (int)(unsigned)(b[s] & 0xFFFFFFFFull); ids[s] = pcol[s]; }
    // sort excluded ids ascending (tiny; every lane duplicates)
    for (int i = 0; i < 4; ++i)
        for (int j = 0; j < 4 - i; ++j)
            if (ids[j] > ids[j + 1]) { int tmp = ids[j]; ids[j] = ids[j + 1]; ids[j + 1] = tmp; }

    // column for this lane: lanes 0..19 = sampled negatives, 20..24 = positives
    int col = row;
    if (lane < 20) {
        unsigned m0 = (unsigned)(row * 20 + lane);
        unsigned hi, lo;
        threefry2x32(0u, 42u, m0, m0 + TOTAL_SAMP, hi, lo);
        unsigned samp = ((hi % SPAN) * MULT + (lo % SPAN)) % SPAN;
        int c = (int)samp;
#pragma unroll
        for (int s = 0; s < 5; ++s) c += (ids[s] <= c) ? 1 : 0;
        col = c;
    } else if (lane < 25) {
        col = pcol[lane - 20];
    }

    // exact fp32 Poincare distance term  -dist/tau  (diagonal -> -inf)
    float term = -INFINITY;
    if (lane < 25 && col != row) {
        const float4* xr = (const float4*)(X + (size_t)row * 64);
        const float4* xc = (const float4*)(X + (size_t)col * 64);
        float dot = 0.f;
#pragma unroll
        for (int k = 0; k < 16; ++k) {
            float4 a = xr[k];
            float4 c = xc[k];
            dot = fmaf(a.x, c.x, dot);
            dot = fmaf(a.y, c.y, dot);
            dot = fmaf(a.z, c.z, dot);
            dot = fmaf(a.w, c.w, dot);
        }
        float nsi = nsiv[row].x, nsj = nsiv[col].x;
        float d2  = fmaxf(nsi + nsj - 2.f * dot, 0.f);
        float ci  = 1.f - fminf(nsi, 1.f);
        float cj  = 1.f - fminf(nsj, 1.f);
        float den = fmaxf(ci * cj, 1e-9f);
        float z   = fmaxf(1.f + 2.f * d2 / den, 1.f);
        term = -acoshf(z) * TAU_INV;
    }

    // two masked LSEs across the wave
    float negt = (lane < 20) ? term : -INFINITY;
    float post = (lane >= 20 && lane < 25) ? term : -INFINITY;

    float nm = wave_maxf(negt);
    float ne = (lane < 20 && negt != -INFINITY) ? expf(negt - nm) : 0.f;
    float neg = nm + logf(wave_sumf(ne));

    float pm = wave_maxf(post);
    float pe = (lane >= 20 && lane < 25) ? expf(post - pm) : 0.f;
    float pos = pm + logf(wave_sumf(pe));

    if (lane == 0) rowloss[row] = neg - pos;
}

// ---------------- Kernel 4: deterministic tree sum ----------------
__global__ void reduce_kernel(const float* __restrict__ rl, float* __restrict__ out) {
    const int t = threadIdx.x;
    float s = 0.f;
#pragma unroll
    for (int i = 0; i < 32; ++i) s += rl[t + 256 * i];
#pragma unroll
    for (int o = 32; o; o >>= 1) s += __shfl_xor(s, o);
    __shared__ float ws4[4];
    if ((t & 63) == 0) ws4[t >> 6] = s;
    __syncthreads();
    if (t == 0) out[0] = (ws4[0] + ws4[1] + ws4[2] + ws4[3]) * (1.0f / 8192.0f);
}

// ---------------- launch ----------------
extern "C" void kernel_launch(void* const* d_in, const int* in_sizes, int n_in,
                              void* d_out, int out_size, void* d_ws, size_t ws_size,
                              hipStream_t stream) {
    (void)in_sizes; (void)n_in; (void)out_size; (void)ws_size;
    const float* X = (const float*)d_in[0];
    float* out = (float*)d_out;

    float2* nsiv    = (float2*)d_ws;                                  // 64 KB
    char*   Xhi     = (char*)d_ws + 65536;                            // 1 MB
    char*   Xlo     = (char*)d_ws + 65536 + 1048576;                  // 1 MB
    ull*    part    = (ull*)((char*)d_ws + 65536 + 2097152);          // 8192*40*8 = 2.5 MB
    float*  rowloss = (float*)((char*)d_ws + 65536 + 2097152 + 2621440); // 32 KB

    prep_kernel<<<256, 256, 0, stream>>>(X, nsiv, Xhi, Xlo);
    gram_topk<<<1024, 256, 0, stream>>>(Xhi, Xlo, nsiv, part);
    finalize_kernel<<<2048, 256, 0, stream>>>(X, nsiv, part, rowloss);
    reduce_kernel<<<1, 256, 0, stream>>>(rowloss, out);
}

// Round 9
// 217.581 us; speedup vs baseline: 1.4780x; 1.0864x over previous
//
#include <hip/hip_runtime.h>
#include <cstdint>
#include <cstddef>

typedef unsigned long long ull;
typedef _Float16 f16x8 __attribute__((ext_vector_type(8)));
typedef float f32x4 __attribute__((ext_vector_type(4)));

#define N_ROWS 8192
#define SPAN   8187u   // n - k
#define MULT   1600u   // (2^32) % 8187
#define TAU_INV 10.0f
#define TOTAL_SAMP 163840u
#define INIT_KEY 0x7F800000FFFFFFFFull   // q=+inf, col=~0
#define NCHUNK 8
#define CHUNK_COLS 1024

// ---------------- threefry2x32 (JAX-compatible) ----------------
__device__ __forceinline__ void tf_round(unsigned &x0, unsigned &x1, int r) {
    x0 += x1; x1 = (x1 << r) | (x1 >> (32 - r)); x1 ^= x0;
}
__device__ __forceinline__ void threefry2x32(unsigned k0, unsigned k1,
                                             unsigned c0, unsigned c1,
                                             unsigned &o0, unsigned &o1) {
    unsigned ks2 = k0 ^ k1 ^ 0x1BD11BDAu;
    unsigned x0 = c0 + k0, x1 = c1 + k1;
    tf_round(x0, x1, 13); tf_round(x0, x1, 15); tf_round(x0, x1, 26); tf_round(x0, x1, 6);
    x0 += k1;  x1 += ks2 + 1u;
    tf_round(x0, x1, 17); tf_round(x0, x1, 29); tf_round(x0, x1, 16); tf_round(x0, x1, 24);
    x0 += ks2; x1 += k0 + 2u;
    tf_round(x0, x1, 13); tf_round(x0, x1, 15); tf_round(x0, x1, 26); tf_round(x0, x1, 6);
    x0 += k0;  x1 += k1 + 3u;
    tf_round(x0, x1, 17); tf_round(x0, x1, 29); tf_round(x0, x1, 16); tf_round(x0, x1, 24);
    x0 += k1;  x1 += ks2 + 4u;
    tf_round(x0, x1, 13); tf_round(x0, x1, 15); tf_round(x0, x1, 26); tf_round(x0, x1, 6);
    x0 += ks2; x1 += k0 + 5u;
    o0 = x0; o1 = x1;
}

__device__ __forceinline__ void insert5(ull* a, ull kk) {
    bool l3 = kk < a[3], l2 = kk < a[2], l1 = kk < a[1], l0 = kk < a[0];
    a[4] = l3 ? a[3] : kk;
    a[3] = l3 ? (l2 ? a[2] : kk) : a[3];
    a[2] = l2 ? (l1 ? a[1] : kk) : a[2];
    a[1] = l1 ? (l0 ? a[0] : kk) : a[1];
    a[0] = l0 ? kk : a[0];
}

__device__ __forceinline__ float wave_maxf(float v) {
#pragma unroll
    for (int o = 32; o; o >>= 1) v = fmaxf(v, __shfl_xor(v, o));
    return v;
}
__device__ __forceinline__ float wave_sumf(float v) {
#pragma unroll
    for (int o = 32; o; o >>= 1) v += __shfl_xor(v, o);
    return v;
}
__device__ __forceinline__ ull wave_minu64(ull v) {
#pragma unroll
    for (int o = 32; o; o >>= 1) {
        ull w = __shfl_xor(v, o);
        v = (w < v) ? w : v;
    }
    return v;
}

// ---------------- Kernel 1: norms + f16 hi/lo split ----------------
__global__ void prep_kernel(const float* __restrict__ X,
                            float2* __restrict__ nsiv,
                            char* __restrict__ Xhi,
                            char* __restrict__ Xlo) {
    int t = blockIdx.x * 256 + threadIdx.x;
    int row = t >> 3, c = t & 7;
    const float4* src = (const float4*)(X + (size_t)row * 64 + c * 8);
    float4 a = src[0], b = src[1];
    float v[8] = {a.x, a.y, a.z, a.w, b.x, b.y, b.z, b.w};
    float ss = 0.f;
#pragma unroll
    for (int j = 0; j < 8; ++j) ss = fmaf(v[j], v[j], ss);
    ss += __shfl_xor(ss, 1);
    ss += __shfl_xor(ss, 2);
    ss += __shfl_xor(ss, 4);
    f16x8 h, l;
#pragma unroll
    for (int j = 0; j < 8; ++j) {
        _Float16 hh = (_Float16)v[j];
        h[j] = hh;
        l[j] = (_Float16)(v[j] - (float)hh);
    }
    *(f16x8*)(Xhi + (size_t)row * 128 + c * 16) = h;
    *(f16x8*)(Xlo + (size_t)row * 128 + c * 16) = l;
    if (c == 0) nsiv[row] = make_float2(ss, 1.0f / (1.0f - fminf(ss, 1.0f)));
}

// ---------------- Kernel 2: MFMA gram + fused top-5 ----------------
// grid 1024 = 128 row-tiles x 8 col-chunks. 4 independent waves/block, no LDS,
// no barriers, no VGPR clamp (r7 lesson). K-loop: 64 iterations x 16 cols with
// a SMALL body pinned by `#pragma unroll 1` -- r8 lesson: large unrolled bodies
// plateau at ~170us with all pipes idle (front-end/I-cache bound signature).
__global__ __launch_bounds__(256) void gram_topk(
        const char* __restrict__ Xhi, const char* __restrict__ Xlo,
        const float2* __restrict__ nsiv, ull* __restrict__ part) {
    const int t = threadIdx.x, lane = t & 63, wv = t >> 6;
    const int lx = lane & 15, lq = lane >> 4;
    const int r0 = (blockIdx.x >> 3) * 64;
    const int ch = blockIdx.x & 7;
    const int j0base = ch * CHUNK_COLS;

    // A fragments straight from global (one-time, 64B/lane)
    f16x8 ahi[2], alo[2];
#pragma unroll
    for (int kc = 0; kc < 2; ++kc) {
        const size_t aoff = (size_t)(r0 + wv * 16 + lx) * 128 + (kc * 4 + lq) * 16;
        ahi[kc] = *(const f16x8*)(Xhi + aoff);
        alo[kc] = *(const f16x8*)(Xlo + aoff);
    }

    // per-lane row stats (C/D layout: row = lq*4 + reg)
    int grow[4]; float rns[4];
#pragma unroll
    for (int r = 0; r < 4; ++r) {
        grow[r] = r0 + wv * 16 + lq * 4 + r;
        rns[r] = nsiv[grow[r]].x;
    }

    ull t5[4][5];
    float thr[4];
#pragma unroll
    for (int r = 0; r < 4; ++r) {
        thr[r] = __builtin_inff();
#pragma unroll
        for (int s = 0; s < 5; ++s) t5[r][s] = INIT_KEY;
    }

#pragma unroll 1
    for (int it = 0; it < CHUNK_COLS / 16; ++it) {   // 64 iters, 16 cols each
        const int gcol = j0base + it * 16 + lx;      // this lane's column
        const int boff = gcol << 7;                  // *128 bytes/row

        f16x8 bh0 = *(const f16x8*)(Xhi + boff + lq * 16);
        f16x8 bh1 = *(const f16x8*)(Xhi + boff + 64 + lq * 16);
        f16x8 bl0 = *(const f16x8*)(Xlo + boff + lq * 16);
        f16x8 bl1 = *(const f16x8*)(Xlo + boff + 64 + lq * 16);
        float2 cnv = nsiv[gcol];

        f32x4 a = {0.f, 0.f, 0.f, 0.f};
        a = __builtin_amdgcn_mfma_f32_16x16x32_f16(ahi[0], bh0, a, 0, 0, 0);
        a = __builtin_amdgcn_mfma_f32_16x16x32_f16(ahi[1], bh1, a, 0, 0, 0);
        a = __builtin_amdgcn_mfma_f32_16x16x32_f16(ahi[0], bl0, a, 0, 0, 0);
        a = __builtin_amdgcn_mfma_f32_16x16x32_f16(ahi[1], bl1, a, 0, 0, 0);
        a = __builtin_amdgcn_mfma_f32_16x16x32_f16(alo[0], bh0, a, 0, 0, 0);
        a = __builtin_amdgcn_mfma_f32_16x16x32_f16(alo[1], bh1, a, 0, 0, 0);

        const float civ    = cnv.y;
        const float cnsciv = cnv.x * civ;
        const float m2civ  = -2.0f * civ;
#pragma unroll
        for (int r = 0; r < 4; ++r) {
            float base = fmaf(rns[r], civ, cnsciv);
            float q    = fmaf(a[r], m2civ, base);
            if (q < thr[r] && gcol != grow[r]) {
                ull kk = ((ull)__float_as_uint(q) << 32) | (unsigned)gcol;
                insert5(t5[r], kk);
                thr[r] = __uint_as_float((unsigned)(t5[r][4] >> 32));
            }
        }
    }

    // shuffle-based merge across the 16 lanes of each lq-group (rows lq*4+r).
    // t5[r] is sorted ascending -> local min is t5[r][0]; removal = shift left.
#pragma unroll
    for (int r = 0; r < 4; ++r) {
        ull outk[5];
#pragma unroll
        for (int s = 0; s < 5; ++s) {
            ull m = t5[r][0];
#pragma unroll
            for (int off = 1; off <= 8; off <<= 1) {
                ull w = __shfl_xor(m, off);
                m = (w < m) ? w : m;
            }
            if (t5[r][0] == m) {   // unique keys (col embedded) -> single owner
                t5[r][0] = t5[r][1]; t5[r][1] = t5[r][2];
                t5[r][2] = t5[r][3]; t5[r][3] = t5[r][4];
                t5[r][4] = ~0ull;
            }
            outk[s] = m;
        }
        if (lx == r) {
            ull* dst = part + (size_t)(r0 + wv * 16 + lq * 4 + r) * (NCHUNK * 5) + ch * 5;
#pragma unroll
            for (int s = 0; s < 5; ++s) dst[s] = outk[s];
        }
    }
}

// ---------------- Kernel 3: finalize, 4 rows/block (wave per row), shuffle-parallel ----------------
__global__ __launch_bounds__(256) void finalize_kernel(
        const float* __restrict__ X, const float2* __restrict__ nsiv,
        const ull* __restrict__ part, float* __restrict__ rowloss) {
    const int t = threadIdx.x, lane = t & 63, wv = t >> 6;
    const int row = blockIdx.x * 4 + wv;

    // merge chunk top-5s (40 keys) -> global top-5 via 5 wave-min passes
    ull key = (lane < NCHUNK * 5) ? part[(size_t)row * (NCHUNK * 5) + lane] : ~0ull;
    ull b[5];
#pragma unroll
    for (int s = 0; s < 5; ++s) {
        ull m = wave_minu64(key);
        b[s] = m;
        if (key == m) key = ~0ull;   // cols unique across chunks -> unique min
    }

    int pcol[5], ids[5];
#pragma unroll
    for (int s = 0; s < 5; ++s) { pcol[s] = (int)(unsigned)(b[s] & 0xFFFFFFFFull); ids[s] = pcol[s]; }
    // sort excluded ids ascending (tiny; every lane duplicates)
    for (int i = 0; i < 4; ++i)
        for (int j = 0; j < 4 - i; ++j)
            if (ids[j] > ids[j + 1]) { int tmp = ids[j]; ids[j] = ids[j + 1]; ids[j + 1] = tmp; }

    // column for this lane: lanes 0..19 = sampled negatives, 20..24 = positives
    int col = row;
    if (lane < 20) {
        unsigned m0 = (unsigned)(row * 20 + lane);
        unsigned hi, lo;
        threefry2x32(0u, 42u, m0, m0 + TOTAL_SAMP, hi, lo);
        unsigned samp = ((hi % SPAN) * MULT + (lo % SPAN)) % SPAN;
        int c = (int)samp;
#pragma unroll
        for (int s = 0; s < 5; ++s) c += (ids[s] <= c) ? 1 : 0;
        col = c;
    } else if (lane < 25) {
        col = pcol[lane - 20];
    }

    // exact fp32 Poincare distance term  -dist/tau  (diagonal -> -inf)
    float term = -INFINITY;
    if (lane < 25 && col != row) {
        const float4* xr = (const float4*)(X + (size_t)row * 64);
        const float4* xc = (const float4*)(X + (size_t)col * 64);
        float dot = 0.f;
#pragma unroll
        for (int k = 0; k < 16; ++k) {
            float4 a = xr[k];
            float4 c = xc[k];
            dot = fmaf(a.x, c.x, dot);
            dot = fmaf(a.y, c.y, dot);
            dot = fmaf(a.z, c.z, dot);
            dot = fmaf(a.w, c.w, dot);
        }
        float nsi = nsiv[row].x, nsj = nsiv[col].x;
        float d2  = fmaxf(nsi + nsj - 2.f * dot, 0.f);
        float ci  = 1.f - fminf(nsi, 1.f);
        float cj  = 1.f - fminf(nsj, 1.f);
        float den = fmaxf(ci * cj, 1e-9f);
        float z   = fmaxf(1.f + 2.f * d2 / den, 1.f);
        term = -acoshf(z) * TAU_INV;
    }

    // two masked LSEs across the wave
    float negt = (lane < 20) ? term : -INFINITY;
    float post = (lane >= 20 && lane < 25) ? term : -INFINITY;

    float nm = wave_maxf(negt);
    float ne = (lane < 20 && negt != -INFINITY) ? expf(negt - nm) : 0.f;
    float neg = nm + logf(wave_sumf(ne));

    float pm = wave_maxf(post);
    float pe = (lane >= 20 && lane < 25) ? expf(post - pm) : 0.f;
    float pos = pm + logf(wave_sumf(pe));

    if (lane == 0) rowloss[row] = neg - pos;
}

// ---------------- Kernel 4: deterministic tree sum (float4 loads) ----------------
__global__ void reduce_kernel(const float* __restrict__ rl, float* __restrict__ out) {
    const int t = threadIdx.x;
    const float4* r4 = (const float4*)rl;
    float s = 0.f;
#pragma unroll
    for (int i = 0; i < 8; ++i) {
        float4 v = r4[t + 256 * i];
        s += (v.x + v.y) + (v.z + v.w);
    }
#pragma unroll
    for (int o = 32; o; o >>= 1) s += __shfl_xor(s, o);
    __shared__ float ws4[4];
    if ((t & 63) == 0) ws4[t >> 6] = s;
    __syncthreads();
    if (t == 0) out[0] = (ws4[0] + ws4[1] + ws4[2] + ws4[3]) * (1.0f / 8192.0f);
}

// ---------------- launch ----------------
extern "C" void kernel_launch(void* const* d_in, const int* in_sizes, int n_in,
                              void* d_out, int out_size, void* d_ws, size_t ws_size,
                              hipStream_t stream) {
    (void)in_sizes; (void)n_in; (void)out_size; (void)ws_size;
    const float* X = (const float*)d_in[0];
    float* out = (float*)d_out;

    float2* nsiv    = (float2*)d_ws;                                  // 64 KB
    char*   Xhi     = (char*)d_ws + 65536;                            // 1 MB
    char*   Xlo     = (char*)d_ws + 65536 + 1048576;                  // 1 MB
    ull*    part    = (ull*)((char*)d_ws + 65536 + 2097152);          // 8192*40*8 = 2.5 MB
    float*  rowloss = (float*)((char*)d_ws + 65536 + 2097152 + 2621440); // 32 KB

    prep_kernel<<<256, 256, 0, stream>>>(X, nsiv, Xhi, Xlo);
    gram_topk<<<1024, 256, 0, stream>>>(Xhi, Xlo, nsiv, part);
    finalize_kernel<<<2048, 256, 0, stream>>>(X, nsiv, part, rowloss);
    reduce_kernel<<<1, 256, 0, stream>>>(rowloss, out);
}